// Round 1
// baseline (5272.729 us; speedup 1.0000x reference)
//
#include <hip/hip_runtime.h>
#include <hip/hip_bf16.h>
#include <cstdint>

// PhaseEncodingSNN: B=64, T=512, I=256, H=512, O=256, fp32 throughout.
// Phases:
//  1) transpose W_hh -> WT[h][g]            (coalesced recurrent matvec reads)
//  2) softmax over t of temporal_attention  -> attn (T,O)
//  3) GEMM1: proj[(b,t),h] = x @ W_in^T + b_in          (M=32768,N=512,K=256)
//  4) LIF scan #1 in-place: proj -> hidden spikes (0/1 fp32)
//  5) GEMM2: rproj[(b,t),g] = proj @ W_ih^T + b_ih      (M=32768,N=512,K=512)
//  6) recurrent scan: 64 blocks (1 per batch), mem in LDS, WT streamed from L2;
//     writes temporal spikes in-place over rproj
//  7) out_stage1: partial[tc][b][o] = sum_{t in chunk} attn[t,o]*(ts[t,b,:]@W_out[o,:])
//     (attn folded into the W_out LDS tile at staging time)
//  8) finalize: attended = b_out + sum_tc partial; out = attended > 1 ? 1 : 0
//     (b_out added once is exact because softmax weights sum to 1 over t)

#define T_STEPS 512
#define BATCH 64
#define HID 512
#define IN_DIM 256
#define OUT_DIM 256
#define BETA 0.9f
#define THR 1.0f

// ---------------------------------------------------------------- transpose
__global__ __launch_bounds__(256) void k_transpose512(
    const float* __restrict__ W, float* __restrict__ WT) {
  __shared__ float tile[32][33];
  const int x = threadIdx.x & 31;
  const int y = threadIdx.x >> 5;  // 0..7
  const int g0 = blockIdx.x * 32, h0 = blockIdx.y * 32;
#pragma unroll
  for (int j = 0; j < 4; ++j) {
    int gy = y + j * 8;
    tile[gy][x] = W[(size_t)(g0 + gy) * HID + h0 + x];
  }
  __syncthreads();
#pragma unroll
  for (int j = 0; j < 4; ++j) {
    int hy = y + j * 8;
    WT[(size_t)(h0 + hy) * HID + g0 + x] = tile[x][hy];
  }
}

// ---------------------------------------------------------------- softmax over t
// grid 8 blocks x 256 thr: o = blk*32 + (tid&31); tgroup = tid>>5 (8 groups x 64 t)
__global__ __launch_bounds__(256) void k_softmax_t(
    const float* __restrict__ TA, float* __restrict__ attn) {
  __shared__ float redm[8][32];
  __shared__ float reds[8][32];
  const int ol = threadIdx.x & 31;
  const int tg = threadIdx.x >> 5;
  const int o = blockIdx.x * 32 + ol;
  float mx = -1e30f;
  for (int i = 0; i < 64; ++i) {
    float v = TA[(size_t)(tg * 64 + i) * OUT_DIM + o];
    mx = fmaxf(mx, v);
  }
  redm[tg][ol] = mx;
  __syncthreads();
  float m = redm[0][ol];
#pragma unroll
  for (int j = 1; j < 8; ++j) m = fmaxf(m, redm[j][ol]);
  float s = 0.f;
  for (int i = 0; i < 64; ++i) {
    float v = TA[(size_t)(tg * 64 + i) * OUT_DIM + o];
    s += __expf(v - m);
  }
  reds[tg][ol] = s;
  __syncthreads();
  float tot = 0.f;
#pragma unroll
  for (int j = 0; j < 8; ++j) tot += reds[j][ol];
  const float inv = 1.0f / tot;
  for (int i = 0; i < 64; ++i) {
    int t = tg * 64 + i;
    float v = TA[(size_t)t * OUT_DIM + o];
    attn[(size_t)t * OUT_DIM + o] = __expf(v - m) * inv;
  }
}

// ---------------------------------------------------------------- tiled GEMM
// C(MxN) = A(MxK) * B(NxK)^T + bias(N). M,N,K multiples of 64/64/32.
// 64x64 tile, 256 threads, 4x4 microtile, LDS stored transposed [k][m]
// (stride 68 floats: 16B-aligned rows, spreads banks).
__global__ __launch_bounds__(256) void k_gemm_nt_bias(
    const float* __restrict__ A, const float* __restrict__ B,
    const float* __restrict__ bias, float* __restrict__ C,
    int M, int N, int K) {
  __shared__ float As[32][68];
  __shared__ float Bs[32][68];
  const int tid = threadIdx.x;
  const int row0 = blockIdx.x * 64;
  const int col0 = blockIdx.y * 64;
  const int tx = tid & 15, ty = tid >> 4;
  float acc[4][4] = {{0.f, 0.f, 0.f, 0.f}};
  for (int k0 = 0; k0 < K; k0 += 32) {
#pragma unroll
    for (int j = 0; j < 2; ++j) {
      int idx = tid + j * 256;
      int r = idx >> 3;
      int k4 = (idx & 7) << 2;
      float4 va = *(const float4*)(&A[(size_t)(row0 + r) * K + k0 + k4]);
      As[k4 + 0][r] = va.x; As[k4 + 1][r] = va.y;
      As[k4 + 2][r] = va.z; As[k4 + 3][r] = va.w;
      float4 vb = *(const float4*)(&B[(size_t)(col0 + r) * K + k0 + k4]);
      Bs[k4 + 0][r] = vb.x; Bs[k4 + 1][r] = vb.y;
      Bs[k4 + 2][r] = vb.z; Bs[k4 + 3][r] = vb.w;
    }
    __syncthreads();
#pragma unroll
    for (int k = 0; k < 32; ++k) {
      float4 a = *(const float4*)(&As[k][ty * 4]);
      float4 b = *(const float4*)(&Bs[k][tx * 4]);
      acc[0][0] = fmaf(a.x, b.x, acc[0][0]); acc[0][1] = fmaf(a.x, b.y, acc[0][1]);
      acc[0][2] = fmaf(a.x, b.z, acc[0][2]); acc[0][3] = fmaf(a.x, b.w, acc[0][3]);
      acc[1][0] = fmaf(a.y, b.x, acc[1][0]); acc[1][1] = fmaf(a.y, b.y, acc[1][1]);
      acc[1][2] = fmaf(a.y, b.z, acc[1][2]); acc[1][3] = fmaf(a.y, b.w, acc[1][3]);
      acc[2][0] = fmaf(a.z, b.x, acc[2][0]); acc[2][1] = fmaf(a.z, b.y, acc[2][1]);
      acc[2][2] = fmaf(a.z, b.z, acc[2][2]); acc[2][3] = fmaf(a.z, b.w, acc[2][3]);
      acc[3][0] = fmaf(a.w, b.x, acc[3][0]); acc[3][1] = fmaf(a.w, b.y, acc[3][1]);
      acc[3][2] = fmaf(a.w, b.z, acc[3][2]); acc[3][3] = fmaf(a.w, b.w, acc[3][3]);
    }
    __syncthreads();
  }
  float4 bv = *(const float4*)(&bias[col0 + tx * 4]);
#pragma unroll
  for (int i = 0; i < 4; ++i) {
    float4 o;
    o.x = acc[i][0] + bv.x; o.y = acc[i][1] + bv.y;
    o.z = acc[i][2] + bv.z; o.w = acc[i][3] + bv.w;
    *(float4*)(&C[(size_t)(row0 + ty * 4 + i) * N + col0 + tx * 4]) = o;
  }
}

// ---------------------------------------------------------------- LIF scan #1
// in-place: proj[(b*T+t)*H + h] -> spike (0/1). One thread per (b,h) chain.
// t-loop unrolled by 8 with batched prefetch loads to cover HBM latency
// (only 2 waves/CU of parallelism here).
__global__ __launch_bounds__(256) void k_lif1(float* __restrict__ p) {
  const int id = blockIdx.x * 256 + threadIdx.x;  // 0..32767
  const size_t base = (size_t)(id >> 9) * (T_STEPS * HID) + (id & 511);
  float mem = 0.f;
  for (int t0 = 0; t0 < T_STEPS; t0 += 8) {
    float v[8];
#pragma unroll
    for (int j = 0; j < 8; ++j) v[j] = p[base + (size_t)(t0 + j) * HID];
#pragma unroll
    for (int j = 0; j < 8; ++j) {
      float nm = BETA * mem + v[j];
      float sp = nm > THR ? 1.0f : 0.0f;
      p[base + (size_t)(t0 + j) * HID] = sp;
      mem = nm - sp;
    }
  }
}

// ---------------------------------------------------------------- recurrent scan
// One block per batch, 512 threads (one per output g). mem[512] in LDS.
// Per step: nm[g] = beta*mem[g] + in_proj[t,g] + sum_h WT[h][g]*mem[h] + b_hh[g]
// WT reads are lane-coalesced (g contiguous); mem read as float4 LDS broadcast.
// Writes temporal spikes in-place over rproj (block owns its batch's rows).
__global__ __launch_bounds__(512) void k_recurrent(
    const float* __restrict__ WT, const float* __restrict__ b_hh,
    float* __restrict__ rp) {
  __shared__ float mem[HID];
  const int g = threadIdx.x;
  const size_t base = (size_t)blockIdx.x * (T_STEPS * HID);
  mem[g] = 0.f;
  const float bh = b_hh[g];
  __syncthreads();
  for (int t = 0; t < T_STEPS; ++t) {
    const float ip = rp[base + (size_t)t * HID + g];
    float a0 = 0.f, a1 = 0.f, a2 = 0.f, a3 = 0.f;
    const float4* m4 = (const float4*)mem;
#pragma unroll 8
    for (int h4 = 0; h4 < HID / 4; ++h4) {
      float4 mv = m4[h4];
      const float* w = WT + (size_t)(h4 << 2) * HID + g;
      a0 = fmaf(w[0 * HID], mv.x, a0);
      a1 = fmaf(w[1 * HID], mv.y, a1);
      a2 = fmaf(w[2 * HID], mv.z, a2);
      a3 = fmaf(w[3 * HID], mv.w, a3);
    }
    const float m_old = mem[g];
    const float nm = BETA * m_old + ip + ((a0 + a1) + (a2 + a3)) + bh;
    const float sp = nm > THR ? 1.0f : 0.0f;
    rp[base + (size_t)t * HID + g] = sp;
    __syncthreads();  // all dot-reads of mem done before update
    mem[g] = nm - sp;
    __syncthreads();
  }
}

// ---------------------------------------------------------------- output stage 1
// Block (bo, tc): o-tile = bo*64..+64, t in [tc*8, tc*8+8).
// partial[tc][b][o] = sum_t attn[t,o] * sum_h ts[(b,t),h] * W_out[o,h]
// attn folded into the W_out LDS tile at staging time.
__global__ __launch_bounds__(256) void k_out_stage1(
    const float* __restrict__ TS, const float* __restrict__ Wout,
    const float* __restrict__ attn, float* __restrict__ part) {
  __shared__ float Ss[32][68];
  __shared__ float Ws[32][68];
  const int tid = threadIdx.x;
  const int o0 = blockIdx.x * 64;
  const int tc = blockIdx.y;
  const int tx = tid & 15, ty = tid >> 4;
  float acc[4][4] = {{0.f, 0.f, 0.f, 0.f}};
  for (int tt = 0; tt < 8; ++tt) {
    const int t = tc * 8 + tt;
    for (int k0 = 0; k0 < HID; k0 += 32) {
#pragma unroll
      for (int j = 0; j < 2; ++j) {
        int idx = tid + j * 256;
        int r = idx >> 3;          // batch index for Ss, o-local for Ws
        int k4 = (idx & 7) << 2;
        float4 vs = *(const float4*)(&TS[(size_t)(r * T_STEPS + t) * HID + k0 + k4]);
        Ss[k4 + 0][r] = vs.x; Ss[k4 + 1][r] = vs.y;
        Ss[k4 + 2][r] = vs.z; Ss[k4 + 3][r] = vs.w;
        float aw = attn[(size_t)t * OUT_DIM + o0 + r];
        float4 vw = *(const float4*)(&Wout[(size_t)(o0 + r) * HID + k0 + k4]);
        Ws[k4 + 0][r] = vw.x * aw; Ws[k4 + 1][r] = vw.y * aw;
        Ws[k4 + 2][r] = vw.z * aw; Ws[k4 + 3][r] = vw.w * aw;
      }
      __syncthreads();
#pragma unroll
      for (int k = 0; k < 32; ++k) {
        float4 a = *(const float4*)(&Ss[k][ty * 4]);   // batch dim
        float4 b = *(const float4*)(&Ws[k][tx * 4]);   // o dim (attn-scaled)
        acc[0][0] = fmaf(a.x, b.x, acc[0][0]); acc[0][1] = fmaf(a.x, b.y, acc[0][1]);
        acc[0][2] = fmaf(a.x, b.z, acc[0][2]); acc[0][3] = fmaf(a.x, b.w, acc[0][3]);
        acc[1][0] = fmaf(a.y, b.x, acc[1][0]); acc[1][1] = fmaf(a.y, b.y, acc[1][1]);
        acc[1][2] = fmaf(a.y, b.z, acc[1][2]); acc[1][3] = fmaf(a.y, b.w, acc[1][3]);
        acc[2][0] = fmaf(a.z, b.x, acc[2][0]); acc[2][1] = fmaf(a.z, b.y, acc[2][1]);
        acc[2][2] = fmaf(a.z, b.z, acc[2][2]); acc[2][3] = fmaf(a.z, b.w, acc[2][3]);
        acc[3][0] = fmaf(a.w, b.x, acc[3][0]); acc[3][1] = fmaf(a.w, b.y, acc[3][1]);
        acc[3][2] = fmaf(a.w, b.z, acc[3][2]); acc[3][3] = fmaf(a.w, b.w, acc[3][3]);
      }
      __syncthreads();
    }
  }
#pragma unroll
  for (int i = 0; i < 4; ++i) {
    float4 o;
    o.x = acc[i][0]; o.y = acc[i][1]; o.z = acc[i][2]; o.w = acc[i][3];
    *(float4*)(&part[(size_t)tc * (BATCH * OUT_DIM) +
                     (size_t)(ty * 4 + i) * OUT_DIM + o0 + tx * 4]) = o;
  }
}

// ---------------------------------------------------------------- finalize
__global__ __launch_bounds__(256) void k_finalize(
    const float* __restrict__ part, const float* __restrict__ b_out,
    float* __restrict__ out) {
  const int id = blockIdx.x * 256 + threadIdx.x;  // 0..16383, = b*256+o
  float s = b_out[id & 255];
  for (int tc = 0; tc < 64; ++tc) s += part[(size_t)tc * (BATCH * OUT_DIM) + id];
  out[id] = s > THR ? 1.0f : 0.0f;
}

// ---------------------------------------------------------------- launch
extern "C" void kernel_launch(void* const* d_in, const int* in_sizes, int n_in,
                              void* d_out, int out_size, void* d_ws, size_t ws_size,
                              hipStream_t stream) {
  (void)in_sizes; (void)n_in; (void)out_size; (void)ws_size;
  const float* x     = (const float*)d_in[0];
  const float* W_in  = (const float*)d_in[1];
  const float* b_in  = (const float*)d_in[2];
  const float* W_ih  = (const float*)d_in[3];
  const float* b_ih  = (const float*)d_in[4];
  const float* W_hh  = (const float*)d_in[5];
  const float* b_hh  = (const float*)d_in[6];
  const float* W_out = (const float*)d_in[7];
  const float* b_out = (const float*)d_in[8];
  const float* TA    = (const float*)d_in[9];

  float* ws = (float*)d_ws;
  float* proj  = ws;                        // 32768*512 = 16.78M floats (spikes1 in-place)
  float* rproj = proj + (size_t)32768 * 512;  // 16.78M floats (temporal spikes in-place)
  float* WT    = rproj + (size_t)32768 * 512; // 262144
  float* attn  = WT + 512 * 512;              // 131072
  float* part  = attn + 512 * 256;            // 64*64*256 = 1.05M floats

  k_transpose512<<<dim3(16, 16), 256, 0, stream>>>(W_hh, WT);
  k_softmax_t<<<8, 256, 0, stream>>>(TA, attn);
  k_gemm_nt_bias<<<dim3(512, 8), 256, 0, stream>>>(x, W_in, b_in, proj,
                                                   32768, 512, 256);
  k_lif1<<<128, 256, 0, stream>>>(proj);
  k_gemm_nt_bias<<<dim3(512, 8), 256, 0, stream>>>(proj, W_ih, b_ih, rproj,
                                                   32768, 512, 512);
  k_recurrent<<<64, 512, 0, stream>>>(WT, b_hh, rproj);
  k_out_stage1<<<dim3(4, 64), 256, 0, stream>>>(rproj, W_out, attn, part);
  k_finalize<<<64, 256, 0, stream>>>(part, b_out, (float*)d_out);
}

// Round 2
// 3285.097 us; speedup vs baseline: 1.6050x; 1.6050x over previous
//
#include <hip/hip_runtime.h>
#include <hip/hip_bf16.h>
#include <cstdint>

// PhaseEncodingSNN: B=64, T=512, I=256, H=512, O=256, fp32 throughout.
// R2 change: distributed W-stationary recurrent scan.
//  - 32 groups x 8 blocks (256 blocks, ~1/CU). Block j of a group holds
//    WT rows [j*64,(j+1)*64) in 64 VGPRs/thread (W read from L2 ONCE,
//    not 1 MB/step/CU like R1 -- that stream was the 4.7 ms bottleneck).
//  - Each group owns 2 batches; block j owns mem[h] for its 64-row slice
//    (updated locally: slice_h == slice_g for the owner).
//  - Per step: partial_j[b][g] = sum_{h in slice} Wreg[h]*memLDS[b][h]
//    (depends only on LOCAL mem slice), exchanged via agent-scope
//    (L3-coherent, sc0/sc1) atomic stores/loads + per-group monotonic
//    arrival counter. Double-buffered by step parity; counter never reset.
//  - Cross-XCD safety: all in-kernel cross-block traffic is agent-scope
//    atomics; kernel-boundary acquire/release fences cover everything else
//    (init-kernel zeroed flags, GEMM-written rproj, spike writes for the
//    next kernel).

#define T_STEPS 512
#define BATCH 64
#define HID 512
#define IN_DIM 256
#define OUT_DIM 256
#define BETA 0.9f
#define THR 1.0f

// ---------------------------------------------------------------- transpose
__global__ __launch_bounds__(256) void k_transpose512(
    const float* __restrict__ W, float* __restrict__ WT) {
  __shared__ float tile[32][33];
  const int x = threadIdx.x & 31;
  const int y = threadIdx.x >> 5;  // 0..7
  const int g0 = blockIdx.x * 32, h0 = blockIdx.y * 32;
#pragma unroll
  for (int j = 0; j < 4; ++j) {
    int gy = y + j * 8;
    tile[gy][x] = W[(size_t)(g0 + gy) * HID + h0 + x];
  }
  __syncthreads();
#pragma unroll
  for (int j = 0; j < 4; ++j) {
    int hy = y + j * 8;
    WT[(size_t)(h0 + hy) * HID + g0 + x] = tile[x][hy];
  }
}

// ---------------------------------------------------------------- init flags
__global__ __launch_bounds__(256) void k_init_flags(unsigned int* __restrict__ f) {
  // 32 groups, one counter each, padded to 32 dwords (128 B) per group.
  const int i = blockIdx.x * 256 + threadIdx.x;
  if (i < 32 * 32) f[i] = 0u;
}

// ---------------------------------------------------------------- softmax over t
__global__ __launch_bounds__(256) void k_softmax_t(
    const float* __restrict__ TA, float* __restrict__ attn) {
  __shared__ float redm[8][32];
  __shared__ float reds[8][32];
  const int ol = threadIdx.x & 31;
  const int tg = threadIdx.x >> 5;
  const int o = blockIdx.x * 32 + ol;
  float mx = -1e30f;
  for (int i = 0; i < 64; ++i) {
    float v = TA[(size_t)(tg * 64 + i) * OUT_DIM + o];
    mx = fmaxf(mx, v);
  }
  redm[tg][ol] = mx;
  __syncthreads();
  float m = redm[0][ol];
#pragma unroll
  for (int j = 1; j < 8; ++j) m = fmaxf(m, redm[j][ol]);
  float s = 0.f;
  for (int i = 0; i < 64; ++i) {
    float v = TA[(size_t)(tg * 64 + i) * OUT_DIM + o];
    s += __expf(v - m);
  }
  reds[tg][ol] = s;
  __syncthreads();
  float tot = 0.f;
#pragma unroll
  for (int j = 0; j < 8; ++j) tot += reds[j][ol];
  const float inv = 1.0f / tot;
  for (int i = 0; i < 64; ++i) {
    int t = tg * 64 + i;
    float v = TA[(size_t)t * OUT_DIM + o];
    attn[(size_t)t * OUT_DIM + o] = __expf(v - m) * inv;
  }
}

// ---------------------------------------------------------------- tiled GEMM
// C(MxN) = A(MxK) * B(NxK)^T + bias(N).
__global__ __launch_bounds__(256) void k_gemm_nt_bias(
    const float* __restrict__ A, const float* __restrict__ B,
    const float* __restrict__ bias, float* __restrict__ C,
    int M, int N, int K) {
  __shared__ float As[32][68];
  __shared__ float Bs[32][68];
  const int tid = threadIdx.x;
  const int row0 = blockIdx.x * 64;
  const int col0 = blockIdx.y * 64;
  const int tx = tid & 15, ty = tid >> 4;
  float acc[4][4] = {{0.f, 0.f, 0.f, 0.f}};
  for (int k0 = 0; k0 < K; k0 += 32) {
#pragma unroll
    for (int j = 0; j < 2; ++j) {
      int idx = tid + j * 256;
      int r = idx >> 3;
      int k4 = (idx & 7) << 2;
      float4 va = *(const float4*)(&A[(size_t)(row0 + r) * K + k0 + k4]);
      As[k4 + 0][r] = va.x; As[k4 + 1][r] = va.y;
      As[k4 + 2][r] = va.z; As[k4 + 3][r] = va.w;
      float4 vb = *(const float4*)(&B[(size_t)(col0 + r) * K + k0 + k4]);
      Bs[k4 + 0][r] = vb.x; Bs[k4 + 1][r] = vb.y;
      Bs[k4 + 2][r] = vb.z; Bs[k4 + 3][r] = vb.w;
    }
    __syncthreads();
#pragma unroll
    for (int k = 0; k < 32; ++k) {
      float4 a = *(const float4*)(&As[k][ty * 4]);
      float4 b = *(const float4*)(&Bs[k][tx * 4]);
      acc[0][0] = fmaf(a.x, b.x, acc[0][0]); acc[0][1] = fmaf(a.x, b.y, acc[0][1]);
      acc[0][2] = fmaf(a.x, b.z, acc[0][2]); acc[0][3] = fmaf(a.x, b.w, acc[0][3]);
      acc[1][0] = fmaf(a.y, b.x, acc[1][0]); acc[1][1] = fmaf(a.y, b.y, acc[1][1]);
      acc[1][2] = fmaf(a.y, b.z, acc[1][2]); acc[1][3] = fmaf(a.y, b.w, acc[1][3]);
      acc[2][0] = fmaf(a.z, b.x, acc[2][0]); acc[2][1] = fmaf(a.z, b.y, acc[2][1]);
      acc[2][2] = fmaf(a.z, b.z, acc[2][2]); acc[2][3] = fmaf(a.z, b.w, acc[2][3]);
      acc[3][0] = fmaf(a.w, b.x, acc[3][0]); acc[3][1] = fmaf(a.w, b.y, acc[3][1]);
      acc[3][2] = fmaf(a.w, b.z, acc[3][2]); acc[3][3] = fmaf(a.w, b.w, acc[3][3]);
    }
    __syncthreads();
  }
  float4 bv = *(const float4*)(&bias[col0 + tx * 4]);
#pragma unroll
  for (int i = 0; i < 4; ++i) {
    float4 o;
    o.x = acc[i][0] + bv.x; o.y = acc[i][1] + bv.y;
    o.z = acc[i][2] + bv.z; o.w = acc[i][3] + bv.w;
    *(float4*)(&C[(size_t)(row0 + ty * 4 + i) * N + col0 + tx * 4]) = o;
  }
}

// ---------------------------------------------------------------- LIF scan #1
__global__ __launch_bounds__(256) void k_lif1(float* __restrict__ p) {
  const int id = blockIdx.x * 256 + threadIdx.x;  // 0..32767
  const size_t base = (size_t)(id >> 9) * (T_STEPS * HID) + (id & 511);
  float mem = 0.f;
  for (int t0 = 0; t0 < T_STEPS; t0 += 8) {
    float v[8];
#pragma unroll
    for (int j = 0; j < 8; ++j) v[j] = p[base + (size_t)(t0 + j) * HID];
#pragma unroll
    for (int j = 0; j < 8; ++j) {
      float nm = BETA * mem + v[j];
      float sp = nm > THR ? 1.0f : 0.0f;
      p[base + (size_t)(t0 + j) * HID] = sp;
      mem = nm - sp;
    }
  }
}

// ---------------------------------------------------------------- recurrent (distributed)
// Grid: 256 blocks x 512 threads. Block = (grp = blk>>3, j = blk&7).
// Group grp owns batches {2*grp, 2*grp+1}; block j owns h-slice [j*64,(j+1)*64).
// Wreg[k] = WT[j*64+k][tid] (64 VGPRs). memLDS[b][k] = mem slice (local).
// Step: partials (local) -> agent stores -> group counter -> agent loads ->
//       reduce+LIF update for owned g == owned h -> local mem update.
__global__ __launch_bounds__(512) void k_recurrent_dist(
    const float* __restrict__ WT, const float* __restrict__ b_hh,
    float* __restrict__ rp, float* __restrict__ P,
    unsigned int* __restrict__ flags) {
  const int tid = threadIdx.x;
  const int grp = blockIdx.x >> 3;
  const int j = blockIdx.x & 7;

  __shared__ float memLDS[2][64];
  if (tid < 128) memLDS[tid >> 6][tid & 63] = 0.f;

  // W slice into registers: 64 rows x (this thread's column g = tid).
  float Wreg[64];
#pragma unroll
  for (int k = 0; k < 64; ++k)
    Wreg[k] = WT[(size_t)((j << 6) + k) * HID + tid];

  // Owner-thread constants (threads 0..127: b = tid>>6, g = j*64 + (tid&63)).
  const int ob = tid >> 6;
  const int ogl = tid & 63;
  const int og = (j << 6) + ogl;
  const size_t ip_base =
      (size_t)(grp * 2 + ob) * (T_STEPS * HID) + og;  // valid for tid<128
  float bhh_v = 0.f;
  if (tid < 128) bhh_v = b_hh[og];

  unsigned int* flagp = flags + grp * 32;
  const size_t grp_stride = 8 * 1024;  // 8 blocks x (2 b x 512 g)

  __syncthreads();

  for (int t = 0; t < T_STEPS; ++t) {
    const int par = t & 1;
    // Prefetch this step's input-projection value (consumed after the sync).
    float ip_v = 0.f;
    if (tid < 128) ip_v = rp[ip_base + (size_t)t * HID];

    // Partial dot over local h-slice, both batches (mem broadcast from LDS).
    float p0 = 0.f, p1 = 0.f;
    const float4* m40 = (const float4*)&memLDS[0][0];
    const float4* m41 = (const float4*)&memLDS[1][0];
#pragma unroll
    for (int k4 = 0; k4 < 16; ++k4) {
      float4 m0 = m40[k4];
      float4 m1 = m41[k4];
      p0 = fmaf(Wreg[4 * k4 + 0], m0.x, p0);
      p0 = fmaf(Wreg[4 * k4 + 1], m0.y, p0);
      p0 = fmaf(Wreg[4 * k4 + 2], m0.z, p0);
      p0 = fmaf(Wreg[4 * k4 + 3], m0.w, p0);
      p1 = fmaf(Wreg[4 * k4 + 0], m1.x, p1);
      p1 = fmaf(Wreg[4 * k4 + 1], m1.y, p1);
      p1 = fmaf(Wreg[4 * k4 + 2], m1.z, p1);
      p1 = fmaf(Wreg[4 * k4 + 3], m1.w, p1);
    }

    // Publish partials (L3-coherent agent stores; double-buffered by parity).
    float* pb = P + ((size_t)par * 32 + grp) * grp_stride + (size_t)j * 1024 + tid;
    __hip_atomic_store(pb, p0, __ATOMIC_RELAXED, __HIP_MEMORY_SCOPE_AGENT);
    __hip_atomic_store(pb + 512, p1, __ATOMIC_RELAXED, __HIP_MEMORY_SCOPE_AGENT);
    __syncthreads();  // drains each thread's stores (vmcnt 0) before arrive

    if (tid == 0) {
      __hip_atomic_fetch_add(flagp, 1u, __ATOMIC_RELEASE, __HIP_MEMORY_SCOPE_AGENT);
      const unsigned int want = 8u * (unsigned int)(t + 1);
      while (__hip_atomic_fetch_add(flagp, 0u, __ATOMIC_RELAXED,
                                    __HIP_MEMORY_SCOPE_AGENT) < want) {
        __builtin_amdgcn_s_sleep(1);
      }
    }
    __syncthreads();

    // Reduce all 8 partials for owned g (== owned h), LIF update, spike write.
    if (tid < 128) {
      const float* rb =
          P + ((size_t)par * 32 + grp) * grp_stride + (size_t)ob * 512 + og;
      float s = 0.f;
#pragma unroll
      for (int jj = 0; jj < 8; ++jj)
        s += __hip_atomic_load(rb + (size_t)jj * 1024, __ATOMIC_RELAXED,
                               __HIP_MEMORY_SCOPE_AGENT);
      const float m_old = memLDS[ob][ogl];
      const float nm = BETA * m_old + ip_v + s + bhh_v;
      const float sp = nm > THR ? 1.0f : 0.0f;
      rp[ip_base + (size_t)t * HID] = sp;  // in-place spike (cached store ok)
      memLDS[ob][ogl] = nm - sp;
    }
    __syncthreads();
  }
}

// ---------------------------------------------------------------- output stage 1
__global__ __launch_bounds__(256) void k_out_stage1(
    const float* __restrict__ TS, const float* __restrict__ Wout,
    const float* __restrict__ attn, float* __restrict__ part) {
  __shared__ float Ss[32][68];
  __shared__ float Ws[32][68];
  const int tid = threadIdx.x;
  const int o0 = blockIdx.x * 64;
  const int tc = blockIdx.y;
  const int tx = tid & 15, ty = tid >> 4;
  float acc[4][4] = {{0.f, 0.f, 0.f, 0.f}};
  for (int tt = 0; tt < 8; ++tt) {
    const int t = tc * 8 + tt;
    for (int k0 = 0; k0 < HID; k0 += 32) {
#pragma unroll
      for (int j = 0; j < 2; ++j) {
        int idx = tid + j * 256;
        int r = idx >> 3;
        int k4 = (idx & 7) << 2;
        float4 vs = *(const float4*)(&TS[(size_t)(r * T_STEPS + t) * HID + k0 + k4]);
        Ss[k4 + 0][r] = vs.x; Ss[k4 + 1][r] = vs.y;
        Ss[k4 + 2][r] = vs.z; Ss[k4 + 3][r] = vs.w;
        float aw = attn[(size_t)t * OUT_DIM + o0 + r];
        float4 vw = *(const float4*)(&Wout[(size_t)(o0 + r) * HID + k0 + k4]);
        Ws[k4 + 0][r] = vw.x * aw; Ws[k4 + 1][r] = vw.y * aw;
        Ws[k4 + 2][r] = vw.z * aw; Ws[k4 + 3][r] = vw.w * aw;
      }
      __syncthreads();
#pragma unroll
      for (int k = 0; k < 32; ++k) {
        float4 a = *(const float4*)(&Ss[k][ty * 4]);
        float4 b = *(const float4*)(&Ws[k][tx * 4]);
        acc[0][0] = fmaf(a.x, b.x, acc[0][0]); acc[0][1] = fmaf(a.x, b.y, acc[0][1]);
        acc[0][2] = fmaf(a.x, b.z, acc[0][2]); acc[0][3] = fmaf(a.x, b.w, acc[0][3]);
        acc[1][0] = fmaf(a.y, b.x, acc[1][0]); acc[1][1] = fmaf(a.y, b.y, acc[1][1]);
        acc[1][2] = fmaf(a.y, b.z, acc[1][2]); acc[1][3] = fmaf(a.y, b.w, acc[1][3]);
        acc[2][0] = fmaf(a.z, b.x, acc[2][0]); acc[2][1] = fmaf(a.z, b.y, acc[2][1]);
        acc[2][2] = fmaf(a.z, b.z, acc[2][2]); acc[2][3] = fmaf(a.z, b.w, acc[2][3]);
        acc[3][0] = fmaf(a.w, b.x, acc[3][0]); acc[3][1] = fmaf(a.w, b.y, acc[3][1]);
        acc[3][2] = fmaf(a.w, b.z, acc[3][2]); acc[3][3] = fmaf(a.w, b.w, acc[3][3]);
      }
      __syncthreads();
    }
  }
#pragma unroll
  for (int i = 0; i < 4; ++i) {
    float4 o;
    o.x = acc[i][0]; o.y = acc[i][1]; o.z = acc[i][2]; o.w = acc[i][3];
    *(float4*)(&part[(size_t)tc * (BATCH * OUT_DIM) +
                     (size_t)(ty * 4 + i) * OUT_DIM + o0 + tx * 4]) = o;
  }
}

// ---------------------------------------------------------------- finalize
__global__ __launch_bounds__(256) void k_finalize(
    const float* __restrict__ part, const float* __restrict__ b_out,
    float* __restrict__ out) {
  const int id = blockIdx.x * 256 + threadIdx.x;  // b*256+o
  float s = b_out[id & 255];
  for (int tc = 0; tc < 64; ++tc) s += part[(size_t)tc * (BATCH * OUT_DIM) + id];
  out[id] = s > THR ? 1.0f : 0.0f;
}

// ---------------------------------------------------------------- launch
extern "C" void kernel_launch(void* const* d_in, const int* in_sizes, int n_in,
                              void* d_out, int out_size, void* d_ws, size_t ws_size,
                              hipStream_t stream) {
  (void)in_sizes; (void)n_in; (void)out_size; (void)ws_size;
  const float* x     = (const float*)d_in[0];
  const float* W_in  = (const float*)d_in[1];
  const float* b_in  = (const float*)d_in[2];
  const float* W_ih  = (const float*)d_in[3];
  const float* b_ih  = (const float*)d_in[4];
  const float* W_hh  = (const float*)d_in[5];
  const float* b_hh  = (const float*)d_in[6];
  const float* W_out = (const float*)d_in[7];
  const float* b_out = (const float*)d_in[8];
  const float* TA    = (const float*)d_in[9];

  float* ws = (float*)d_ws;
  float* proj  = ws;                           // 16.78M floats
  float* rproj = proj + (size_t)32768 * 512;   // 16.78M floats
  float* WT    = rproj + (size_t)32768 * 512;  // 262144
  float* attn  = WT + 512 * 512;               // 131072
  float* part  = attn + 512 * 256;             // 1.05M
  float* Pbuf  = part + (size_t)64 * 64 * 256; // 2*32*8*1024 = 524288
  unsigned int* flags = (unsigned int*)(Pbuf + (size_t)2 * 32 * 8 * 1024);  // 1024 dw

  k_init_flags<<<4, 256, 0, stream>>>(flags);
  k_transpose512<<<dim3(16, 16), 256, 0, stream>>>(W_hh, WT);
  k_softmax_t<<<8, 256, 0, stream>>>(TA, attn);
  k_gemm_nt_bias<<<dim3(512, 8), 256, 0, stream>>>(x, W_in, b_in, proj,
                                                   32768, 512, 256);
  k_lif1<<<128, 256, 0, stream>>>(proj);
  k_gemm_nt_bias<<<dim3(512, 8), 256, 0, stream>>>(proj, W_ih, b_ih, rproj,
                                                   32768, 512, 512);
  k_recurrent_dist<<<256, 512, 0, stream>>>(WT, b_hh, rproj, Pbuf, flags);
  k_out_stage1<<<dim3(4, 64), 256, 0, stream>>>(rproj, W_out, attn, part);
  k_finalize<<<64, 256, 0, stream>>>(part, b_out, (float*)d_out);
}

// Round 3
// 1420.594 us; speedup vs baseline: 3.7116x; 2.3125x over previous
//
#include <hip/hip_runtime.h>
#include <hip/hip_bf16.h>
#include <cstdint>

// PhaseEncodingSNN: B=64, T=512, I=256, H=512, O=256, fp32 throughout.
// R3 change: column-parallel recurrent scan with sentinel-data exchange.
//  - 32 groups x 8 blocks. Block j holds W_hh rows [j*64,(j+1)*64) x all h
//    in 64 VGPRs/thread and computes the FULL dot for its own 64 outputs
//    (8-way seg split reduced through LDS). Only the updated mem slice
//    (2 batches x 64 floats = 512 B/block/step) is exchanged.
//  - Exchange: T-deep slot buffer (aliases dead `proj`), pre-filled with
//    quiet-NaN bit pattern. Readers poll the exact dwords they need with
//    relaxed agent-scope loads until != NaN sentinel. No flags, no counter,
//    no reuse handshake -> single store-visibility + poll-detect hop per step.
//  - Membranes are always finite => sentinel unambiguous. The harness's 0xAA
//    ws-poison is NOT NaN, hence the explicit fill kernel each launch.

#define T_STEPS 512
#define BATCH 64
#define HID 512
#define IN_DIM 256
#define OUT_DIM 256
#define BETA 0.9f
#define THR 1.0f
#define SENT 0x7FC00000u

// ---------------------------------------------------------------- NaN fill
// Fills P (32768*512 floats, aliases proj) with the sentinel bit pattern.
__global__ __launch_bounds__(256) void k_fill_nan(uint32_t* __restrict__ P) {
  const int idx = blockIdx.x * 256 + threadIdx.x;  // 65536 threads
  uint4 s = make_uint4(SENT, SENT, SENT, SENT);
  uint4* p4 = (uint4*)P;
  for (int i = idx; i < (32768 * 512) / 4; i += 65536) p4[i] = s;
}

// ---------------------------------------------------------------- softmax over t
__global__ __launch_bounds__(256) void k_softmax_t(
    const float* __restrict__ TA, float* __restrict__ attn) {
  __shared__ float redm[8][32];
  __shared__ float reds[8][32];
  const int ol = threadIdx.x & 31;
  const int tg = threadIdx.x >> 5;
  const int o = blockIdx.x * 32 + ol;
  float mx = -1e30f;
  for (int i = 0; i < 64; ++i) {
    float v = TA[(size_t)(tg * 64 + i) * OUT_DIM + o];
    mx = fmaxf(mx, v);
  }
  redm[tg][ol] = mx;
  __syncthreads();
  float m = redm[0][ol];
#pragma unroll
  for (int j = 1; j < 8; ++j) m = fmaxf(m, redm[j][ol]);
  float s = 0.f;
  for (int i = 0; i < 64; ++i) {
    float v = TA[(size_t)(tg * 64 + i) * OUT_DIM + o];
    s += __expf(v - m);
  }
  reds[tg][ol] = s;
  __syncthreads();
  float tot = 0.f;
#pragma unroll
  for (int j = 0; j < 8; ++j) tot += reds[j][ol];
  const float inv = 1.0f / tot;
  for (int i = 0; i < 64; ++i) {
    int t = tg * 64 + i;
    float v = TA[(size_t)t * OUT_DIM + o];
    attn[(size_t)t * OUT_DIM + o] = __expf(v - m) * inv;
  }
}

// ---------------------------------------------------------------- tiled GEMM
// C(MxN) = A(MxK) * B(NxK)^T + bias(N).
__global__ __launch_bounds__(256) void k_gemm_nt_bias(
    const float* __restrict__ A, const float* __restrict__ B,
    const float* __restrict__ bias, float* __restrict__ C,
    int M, int N, int K) {
  __shared__ float As[32][68];
  __shared__ float Bs[32][68];
  const int tid = threadIdx.x;
  const int row0 = blockIdx.x * 64;
  const int col0 = blockIdx.y * 64;
  const int tx = tid & 15, ty = tid >> 4;
  float acc[4][4] = {{0.f, 0.f, 0.f, 0.f}};
  for (int k0 = 0; k0 < K; k0 += 32) {
#pragma unroll
    for (int j = 0; j < 2; ++j) {
      int idx = tid + j * 256;
      int r = idx >> 3;
      int k4 = (idx & 7) << 2;
      float4 va = *(const float4*)(&A[(size_t)(row0 + r) * K + k0 + k4]);
      As[k4 + 0][r] = va.x; As[k4 + 1][r] = va.y;
      As[k4 + 2][r] = va.z; As[k4 + 3][r] = va.w;
      float4 vb = *(const float4*)(&B[(size_t)(col0 + r) * K + k0 + k4]);
      Bs[k4 + 0][r] = vb.x; Bs[k4 + 1][r] = vb.y;
      Bs[k4 + 2][r] = vb.z; Bs[k4 + 3][r] = vb.w;
    }
    __syncthreads();
#pragma unroll
    for (int k = 0; k < 32; ++k) {
      float4 a = *(const float4*)(&As[k][ty * 4]);
      float4 b = *(const float4*)(&Bs[k][tx * 4]);
      acc[0][0] = fmaf(a.x, b.x, acc[0][0]); acc[0][1] = fmaf(a.x, b.y, acc[0][1]);
      acc[0][2] = fmaf(a.x, b.z, acc[0][2]); acc[0][3] = fmaf(a.x, b.w, acc[0][3]);
      acc[1][0] = fmaf(a.y, b.x, acc[1][0]); acc[1][1] = fmaf(a.y, b.y, acc[1][1]);
      acc[1][2] = fmaf(a.y, b.z, acc[1][2]); acc[1][3] = fmaf(a.y, b.w, acc[1][3]);
      acc[2][0] = fmaf(a.z, b.x, acc[2][0]); acc[2][1] = fmaf(a.z, b.y, acc[2][1]);
      acc[2][2] = fmaf(a.z, b.z, acc[2][2]); acc[2][3] = fmaf(a.z, b.w, acc[2][3]);
      acc[3][0] = fmaf(a.w, b.x, acc[3][0]); acc[3][1] = fmaf(a.w, b.y, acc[3][1]);
      acc[3][2] = fmaf(a.w, b.z, acc[3][2]); acc[3][3] = fmaf(a.w, b.w, acc[3][3]);
    }
    __syncthreads();
  }
  float4 bv = *(const float4*)(&bias[col0 + tx * 4]);
#pragma unroll
  for (int i = 0; i < 4; ++i) {
    float4 o;
    o.x = acc[i][0] + bv.x; o.y = acc[i][1] + bv.y;
    o.z = acc[i][2] + bv.z; o.w = acc[i][3] + bv.w;
    *(float4*)(&C[(size_t)(row0 + ty * 4 + i) * N + col0 + tx * 4]) = o;
  }
}

// ---------------------------------------------------------------- LIF scan #1
__global__ __launch_bounds__(256) void k_lif1(float* __restrict__ p) {
  const int id = blockIdx.x * 256 + threadIdx.x;  // 0..32767
  const size_t base = (size_t)(id >> 9) * (T_STEPS * HID) + (id & 511);
  float mem = 0.f;
  for (int t0 = 0; t0 < T_STEPS; t0 += 8) {
    float v[8];
#pragma unroll
    for (int j = 0; j < 8; ++j) v[j] = p[base + (size_t)(t0 + j) * HID];
#pragma unroll
    for (int j = 0; j < 8; ++j) {
      float nm = BETA * mem + v[j];
      float sp = nm > THR ? 1.0f : 0.0f;
      p[base + (size_t)(t0 + j) * HID] = sp;
      mem = nm - sp;
    }
  }
}

// ---------------------------------------------------------------- recurrent scan
// Grid: 256 blocks x 512 threads. Block = (grp = blk>>3, j = blk&7).
// Group owns batches {2grp, 2grp+1}; block j owns outputs g in [j*64,(j+1)*64).
// Thread (seg = tid>>6, gl = tid&63) holds W_hh[j*64+gl][seg*64 .. seg*64+64)
// in 64 VGPRs. Per step: seg-partial dot from full-mem LDS copy -> LDS reduce
// -> owners (tid<128) LIF-update own slice, write spike, publish mem slice to
// slot t -> all blocks poll slot t's remote dwords (NaN sentinel) for t+1.
__global__ __launch_bounds__(512) void k_recurrent_cp(
    const float* __restrict__ W, const float* __restrict__ b_hh,
    float* __restrict__ rp, float* __restrict__ P) {
  const int tid = threadIdx.x;
  const int grp = blockIdx.x >> 3;
  const int j = blockIdx.x & 7;
  const int seg = tid >> 6;
  const int gl = tid & 63;
  const int g0 = j << 6;

  __shared__ float memLDS[2][HID];
  __shared__ float scratch[8][2][64];

  for (int i = tid; i < 2 * HID; i += 512) ((float*)memLDS)[i] = 0.f;

  // W slice into registers (one-time, L3-served: all blocks read same 1 MB).
  float Wreg[64];
  {
    const float* wrow = W + (size_t)(g0 + gl) * HID + (seg << 6);
#pragma unroll
    for (int k4 = 0; k4 < 16; ++k4) {
      float4 w = *(const float4*)(wrow + 4 * k4);
      Wreg[4 * k4 + 0] = w.x; Wreg[4 * k4 + 1] = w.y;
      Wreg[4 * k4 + 2] = w.z; Wreg[4 * k4 + 3] = w.w;
    }
  }

  // Owner mapping (tid < 128): b = tid>>6, own g = g0 + (tid&63).
  const int ob = tid >> 6;
  const int ogl = tid & 63;
  const int og = g0 + ogl;
  const size_t rp_base = (size_t)(grp * 2 + ob) * (T_STEPS * HID) + og;
  float bhh_v = 0.f;
  if (tid < 128) bhh_v = b_hh[og];

  // Remote-poll mapping (tid < 448): remote g skipping own 64-slice.
  const int rg = (tid < g0) ? tid : tid + 64;

  const uint32_t* Pu = (const uint32_t*)P;
  float* Pf = P;

  __syncthreads();

  for (int t = 0; t < T_STEPS; ++t) {
    // Prefetch this step's input projection (hidden behind the poll).
    float ip_v = 0.f;
    if (tid < 128) ip_v = rp[rp_base + (size_t)t * HID];

    if (t > 0 && tid < 448) {
      const size_t slot = ((size_t)(t - 1) * 32 + grp) * 1024;
      uint32_t u0 = __hip_atomic_load(Pu + slot + rg, __ATOMIC_RELAXED,
                                      __HIP_MEMORY_SCOPE_AGENT);
      uint32_t u1 = __hip_atomic_load(Pu + slot + 512 + rg, __ATOMIC_RELAXED,
                                      __HIP_MEMORY_SCOPE_AGENT);
      while (u0 == SENT || u1 == SENT) {
        __builtin_amdgcn_s_sleep(1);
        if (u0 == SENT)
          u0 = __hip_atomic_load(Pu + slot + rg, __ATOMIC_RELAXED,
                                 __HIP_MEMORY_SCOPE_AGENT);
        if (u1 == SENT)
          u1 = __hip_atomic_load(Pu + slot + 512 + rg, __ATOMIC_RELAXED,
                                 __HIP_MEMORY_SCOPE_AGENT);
      }
      memLDS[0][rg] = __uint_as_float(u0);
      memLDS[1][rg] = __uint_as_float(u1);
    }
    __syncthreads();  // full mem (owners wrote own slice last step; pollers remote)

    // Partial dot over h in [seg*64, seg*64+64), both batches.
    float p0a = 0.f, p0b = 0.f, p1a = 0.f, p1b = 0.f;
    {
      const float4* m0 = (const float4*)&memLDS[0][seg << 6];
      const float4* m1 = (const float4*)&memLDS[1][seg << 6];
#pragma unroll
      for (int k4 = 0; k4 < 16; ++k4) {
        float4 a = m0[k4];
        float4 b = m1[k4];
        p0a = fmaf(Wreg[4 * k4 + 0], a.x, p0a);
        p0b = fmaf(Wreg[4 * k4 + 1], a.y, p0b);
        p0a = fmaf(Wreg[4 * k4 + 2], a.z, p0a);
        p0b = fmaf(Wreg[4 * k4 + 3], a.w, p0b);
        p1a = fmaf(Wreg[4 * k4 + 0], b.x, p1a);
        p1b = fmaf(Wreg[4 * k4 + 1], b.y, p1b);
        p1a = fmaf(Wreg[4 * k4 + 2], b.z, p1a);
        p1b = fmaf(Wreg[4 * k4 + 3], b.w, p1b);
      }
    }
    scratch[seg][0][gl] = p0a + p0b;
    scratch[seg][1][gl] = p1a + p1b;
    __syncthreads();

    if (tid < 128) {
      float s = 0.f;
#pragma unroll
      for (int ss = 0; ss < 8; ++ss) s += scratch[ss][ob][ogl];
      const float m_old = memLDS[ob][og];
      const float nm = BETA * m_old + ip_v + s + bhh_v;
      const float sp = nm > THR ? 1.0f : 0.0f;
      rp[rp_base + (size_t)t * HID] = sp;  // spike in-place (own rows)
      const float mnew = nm - sp;
      memLDS[ob][og] = mnew;  // own slice locally (read after next barrier)
      const size_t slot = ((size_t)t * 32 + grp) * 1024;
      __hip_atomic_store(Pf + slot + (size_t)ob * 512 + og, mnew,
                         __ATOMIC_RELAXED, __HIP_MEMORY_SCOPE_AGENT);
    }
    // No barrier: next iteration's post-poll barrier orders memLDS/scratch.
  }
}

// ---------------------------------------------------------------- output stage 1
__global__ __launch_bounds__(256) void k_out_stage1(
    const float* __restrict__ TS, const float* __restrict__ Wout,
    const float* __restrict__ attn, float* __restrict__ part) {
  __shared__ float Ss[32][68];
  __shared__ float Ws[32][68];
  const int tid = threadIdx.x;
  const int o0 = blockIdx.x * 64;
  const int tc = blockIdx.y;
  const int tx = tid & 15, ty = tid >> 4;
  float acc[4][4] = {{0.f, 0.f, 0.f, 0.f}};
  for (int tt = 0; tt < 8; ++tt) {
    const int t = tc * 8 + tt;
    for (int k0 = 0; k0 < HID; k0 += 32) {
#pragma unroll
      for (int j = 0; j < 2; ++j) {
        int idx = tid + j * 256;
        int r = idx >> 3;
        int k4 = (idx & 7) << 2;
        float4 vs = *(const float4*)(&TS[(size_t)(r * T_STEPS + t) * HID + k0 + k4]);
        Ss[k4 + 0][r] = vs.x; Ss[k4 + 1][r] = vs.y;
        Ss[k4 + 2][r] = vs.z; Ss[k4 + 3][r] = vs.w;
        float aw = attn[(size_t)t * OUT_DIM + o0 + r];
        float4 vw = *(const float4*)(&Wout[(size_t)(o0 + r) * HID + k0 + k4]);
        Ws[k4 + 0][r] = vw.x * aw; Ws[k4 + 1][r] = vw.y * aw;
        Ws[k4 + 2][r] = vw.z * aw; Ws[k4 + 3][r] = vw.w * aw;
      }
      __syncthreads();
#pragma unroll
      for (int k = 0; k < 32; ++k) {
        float4 a = *(const float4*)(&Ss[k][ty * 4]);
        float4 b = *(const float4*)(&Ws[k][tx * 4]);
        acc[0][0] = fmaf(a.x, b.x, acc[0][0]); acc[0][1] = fmaf(a.x, b.y, acc[0][1]);
        acc[0][2] = fmaf(a.x, b.z, acc[0][2]); acc[0][3] = fmaf(a.x, b.w, acc[0][3]);
        acc[1][0] = fmaf(a.y, b.x, acc[1][0]); acc[1][1] = fmaf(a.y, b.y, acc[1][1]);
        acc[1][2] = fmaf(a.y, b.z, acc[1][2]); acc[1][3] = fmaf(a.y, b.w, acc[1][3]);
        acc[2][0] = fmaf(a.z, b.x, acc[2][0]); acc[2][1] = fmaf(a.z, b.y, acc[2][1]);
        acc[2][2] = fmaf(a.z, b.z, acc[2][2]); acc[2][3] = fmaf(a.z, b.w, acc[2][3]);
        acc[3][0] = fmaf(a.w, b.x, acc[3][0]); acc[3][1] = fmaf(a.w, b.y, acc[3][1]);
        acc[3][2] = fmaf(a.w, b.z, acc[3][2]); acc[3][3] = fmaf(a.w, b.w, acc[3][3]);
      }
      __syncthreads();
    }
  }
#pragma unroll
  for (int i = 0; i < 4; ++i) {
    float4 o;
    o.x = acc[i][0]; o.y = acc[i][1]; o.z = acc[i][2]; o.w = acc[i][3];
    *(float4*)(&part[(size_t)tc * (BATCH * OUT_DIM) +
                     (size_t)(ty * 4 + i) * OUT_DIM + o0 + tx * 4]) = o;
  }
}

// ---------------------------------------------------------------- finalize
__global__ __launch_bounds__(256) void k_finalize(
    const float* __restrict__ part, const float* __restrict__ b_out,
    float* __restrict__ out) {
  const int id = blockIdx.x * 256 + threadIdx.x;  // b*256+o
  float s = b_out[id & 255];
  for (int tc = 0; tc < 64; ++tc) s += part[(size_t)tc * (BATCH * OUT_DIM) + id];
  out[id] = s > THR ? 1.0f : 0.0f;
}

// ---------------------------------------------------------------- launch
extern "C" void kernel_launch(void* const* d_in, const int* in_sizes, int n_in,
                              void* d_out, int out_size, void* d_ws, size_t ws_size,
                              hipStream_t stream) {
  (void)in_sizes; (void)n_in; (void)out_size; (void)ws_size;
  const float* x     = (const float*)d_in[0];
  const float* W_in  = (const float*)d_in[1];
  const float* b_in  = (const float*)d_in[2];
  const float* W_ih  = (const float*)d_in[3];
  const float* b_ih  = (const float*)d_in[4];
  const float* W_hh  = (const float*)d_in[5];
  const float* b_hh  = (const float*)d_in[6];
  const float* W_out = (const float*)d_in[7];
  const float* b_out = (const float*)d_in[8];
  const float* TA    = (const float*)d_in[9];

  float* ws = (float*)d_ws;
  float* proj  = ws;                           // 16.78M floats; reused as P after GEMM2
  float* rproj = proj + (size_t)32768 * 512;   // 16.78M floats
  float* attn  = rproj + (size_t)32768 * 512;  // 131072
  float* part  = attn + 512 * 256;             // 1.05M
  float* P     = proj;  // exchange slots: [t][grp][b][g] = 512*32*1024 floats

  k_softmax_t<<<8, 256, 0, stream>>>(TA, attn);
  k_gemm_nt_bias<<<dim3(512, 8), 256, 0, stream>>>(x, W_in, b_in, proj,
                                                   32768, 512, 256);
  k_lif1<<<128, 256, 0, stream>>>(proj);
  k_gemm_nt_bias<<<dim3(512, 8), 256, 0, stream>>>(proj, W_ih, b_ih, rproj,
                                                   32768, 512, 512);
  k_fill_nan<<<256, 256, 0, stream>>>((uint32_t*)P);  // after GEMM2: proj is dead
  k_recurrent_cp<<<256, 512, 0, stream>>>(W_hh, b_hh, rproj, P);
  k_out_stage1<<<dim3(4, 64), 256, 0, stream>>>(rproj, W_out, attn, part);
  k_finalize<<<64, 256, 0, stream>>>(part, b_out, (float*)d_out);
}

// Round 4
// 1071.160 us; speedup vs baseline: 4.9224x; 1.3262x over previous
//
#include <hip/hip_runtime.h>
#include <hip/hip_bf16.h>
#include <cstdint>

// PhaseEncodingSNN: B=64, T=512, I=256, H=512, O=256.
// R4 change: all three big GEMMs moved to bf16 MFMA (16x16x32) with fp32-
// accurate split operands; recurrent scan kept byte-identical to R3.
//  - GEMM1 (x @ W_in^T):   A,B both split hi/lo bf16 -> 3 MFMA terms.
//  - GEMM2 (spk @ W_ih^T): A = spikes, EXACT in bf16 (bit-truncate 0/1 during
//    LDS staging); B split -> 2 terms.
//  - GEMM3 (tspk @ W_out^T): same 2-term trick, no bias; softmax-attention
//    weights + b_out folded in k_attend (exact: sum_t attn == 1).
// Aliasing: x splits live in dead rproj prefix; P aliases proj (post-GEMM2);
// out_proj aliases proj (post-recurrent). Peak ws == R1-proven footprint.

#define T_STEPS 512
#define BATCH 64
#define HID 512
#define IN_DIM 256
#define OUT_DIM 256
#define BETA 0.9f
#define THR 1.0f
#define SENT 0x7FC00000u

typedef __attribute__((ext_vector_type(8))) short short8;
typedef __attribute__((ext_vector_type(4))) float float4v;
typedef unsigned short ushort_t;

// ---------------------------------------------------------------- NaN fill
__global__ __launch_bounds__(256) void k_fill_nan(uint32_t* __restrict__ P) {
  const int idx = blockIdx.x * 256 + threadIdx.x;  // 65536 threads
  uint4 s = make_uint4(SENT, SENT, SENT, SENT);
  uint4* p4 = (uint4*)P;
  for (int i = idx; i < (32768 * 512) / 4; i += 65536) p4[i] = s;
}

// ---------------------------------------------------------------- fp32 -> hi/lo bf16 split
__global__ __launch_bounds__(256) void k_split(const float* __restrict__ src,
                                               ushort_t* __restrict__ hi,
                                               ushort_t* __restrict__ lo, int n) {
  int i = blockIdx.x * 256 + threadIdx.x;
  const int stride = gridDim.x * 256;
  for (; i < n; i += stride) {
    float v = src[i];
    uint32_t u = __float_as_uint(v);
    uint32_t rh = u + 0x7FFFu + ((u >> 16) & 1u);   // RNE to bf16
    ushort_t h = (ushort_t)(rh >> 16);
    float hf = __uint_as_float(((uint32_t)h) << 16);
    float l = v - hf;
    uint32_t ul = __float_as_uint(l);
    uint32_t rl = ul + 0x7FFFu + ((ul >> 16) & 1u);
    hi[i] = h;
    lo[i] = (ushort_t)(rl >> 16);
  }
}

// ---------------------------------------------------------------- softmax over t
__global__ __launch_bounds__(256) void k_softmax_t(
    const float* __restrict__ TA, float* __restrict__ attn) {
  __shared__ float redm[8][32];
  __shared__ float reds[8][32];
  const int ol = threadIdx.x & 31;
  const int tg = threadIdx.x >> 5;
  const int o = blockIdx.x * 32 + ol;
  float mx = -1e30f;
  for (int i = 0; i < 64; ++i) {
    float v = TA[(size_t)(tg * 64 + i) * OUT_DIM + o];
    mx = fmaxf(mx, v);
  }
  redm[tg][ol] = mx;
  __syncthreads();
  float m = redm[0][ol];
#pragma unroll
  for (int j = 1; j < 8; ++j) m = fmaxf(m, redm[j][ol]);
  float s = 0.f;
  for (int i = 0; i < 64; ++i) {
    float v = TA[(size_t)(tg * 64 + i) * OUT_DIM + o];
    s += __expf(v - m);
  }
  reds[tg][ol] = s;
  __syncthreads();
  float tot = 0.f;
#pragma unroll
  for (int j = 0; j < 8; ++j) tot += reds[j][ol];
  const float inv = 1.0f / tot;
  for (int i = 0; i < 64; ++i) {
    int t = tg * 64 + i;
    float v = TA[(size_t)t * OUT_DIM + o];
    attn[(size_t)t * OUT_DIM + o] = __expf(v - m) * inv;
  }
}

// ---------------------------------------------------------------- MFMA GEMM, 3-term split
// C(MxN) = (Ahi+Alo)(Bhi+Blo)^T + bias, dropping lo*lo. 128x128 tile, BK=32,
// 4 waves each computing a 64x64 quadrant as 4x4 of 16x16x32 MFMA tiles.
// LDS rows padded to 40 ushorts (80 B): m/m+8 2-way bank alias only (free).
__global__ __launch_bounds__(256) void k_gemm_split3(
    const ushort_t* __restrict__ Ahi, const ushort_t* __restrict__ Alo,
    const ushort_t* __restrict__ Bhi, const ushort_t* __restrict__ Blo,
    const float* __restrict__ bias, float* __restrict__ C,
    int M, int N, int K) {
  __shared__ ushort_t At[2][128 * 40];
  __shared__ ushort_t Bt[2][128 * 40];
  const int tid = threadIdx.x;
  const int row0 = blockIdx.x * 128, col0 = blockIdx.y * 128;
  const int w = tid >> 6, lane = tid & 63;
  const int wm = (w >> 1) * 64, wn = (w & 1) * 64;
  const int l15 = lane & 15, quad = lane >> 4;
  float4v acc[4][4];
#pragma unroll
  for (int i = 0; i < 4; ++i)
#pragma unroll
    for (int j = 0; j < 4; ++j) acc[i][j] = (float4v){0.f, 0.f, 0.f, 0.f};

  for (int k0 = 0; k0 < K; k0 += 32) {
#pragma unroll
    for (int it = 0; it < 2; ++it) {
      int idx = it * 256 + tid;          // 0..511
      int r = idx >> 2;                  // row 0..127
      int c8 = (idx & 3) << 3;           // k-offset {0,8,16,24}
      *(uint4*)(&At[0][r * 40 + c8]) =
          *(const uint4*)(&Ahi[(size_t)(row0 + r) * K + k0 + c8]);
      *(uint4*)(&At[1][r * 40 + c8]) =
          *(const uint4*)(&Alo[(size_t)(row0 + r) * K + k0 + c8]);
      *(uint4*)(&Bt[0][r * 40 + c8]) =
          *(const uint4*)(&Bhi[(size_t)(col0 + r) * K + k0 + c8]);
      *(uint4*)(&Bt[1][r * 40 + c8]) =
          *(const uint4*)(&Blo[(size_t)(col0 + r) * K + k0 + c8]);
    }
    __syncthreads();
    short8 ah[4], al[4], bh[4], bl[4];
    const int koff = quad * 8;
#pragma unroll
    for (int i = 0; i < 4; ++i) {
      ah[i] = *(const short8*)(&At[0][(wm + i * 16 + l15) * 40 + koff]);
      al[i] = *(const short8*)(&At[1][(wm + i * 16 + l15) * 40 + koff]);
      bh[i] = *(const short8*)(&Bt[0][(wn + i * 16 + l15) * 40 + koff]);
      bl[i] = *(const short8*)(&Bt[1][(wn + i * 16 + l15) * 40 + koff]);
    }
#pragma unroll
    for (int i = 0; i < 4; ++i)
#pragma unroll
      for (int j = 0; j < 4; ++j) {
        acc[i][j] = __builtin_amdgcn_mfma_f32_16x16x32_bf16(ah[i], bh[j], acc[i][j], 0, 0, 0);
        acc[i][j] = __builtin_amdgcn_mfma_f32_16x16x32_bf16(ah[i], bl[j], acc[i][j], 0, 0, 0);
        acc[i][j] = __builtin_amdgcn_mfma_f32_16x16x32_bf16(al[i], bh[j], acc[i][j], 0, 0, 0);
      }
    __syncthreads();
  }
#pragma unroll
  for (int j = 0; j < 4; ++j) {
    const int col = col0 + wn + j * 16 + l15;
    const float bv = bias ? bias[col] : 0.f;
#pragma unroll
    for (int i = 0; i < 4; ++i) {
#pragma unroll
      for (int r = 0; r < 4; ++r) {
        int row = row0 + wm + i * 16 + quad * 4 + r;
        C[(size_t)row * N + col] = acc[i][j][r] + bv;
      }
    }
  }
}

// ---------------------------------------------------------------- MFMA GEMM, spike-A 2-term
// A is fp32 with values EXACTLY 0.0/1.0 -> bf16 by bit-truncation at staging.
// C = A(Bhi+Blo)^T + bias. 128x128 tile, BK=64, same wave layout as split3.
__global__ __launch_bounds__(256) void k_gemm_spike2(
    const float* __restrict__ A, const ushort_t* __restrict__ Bhi,
    const ushort_t* __restrict__ Blo, const float* __restrict__ bias,
    float* __restrict__ C, int M, int N, int K) {
  __shared__ ushort_t At[128 * 72];
  __shared__ ushort_t Bt[2][128 * 72];
  const int tid = threadIdx.x;
  const int row0 = blockIdx.x * 128, col0 = blockIdx.y * 128;
  const int w = tid >> 6, lane = tid & 63;
  const int wm = (w >> 1) * 64, wn = (w & 1) * 64;
  const int l15 = lane & 15, quad = lane >> 4;
  float4v acc[4][4];
#pragma unroll
  for (int i = 0; i < 4; ++i)
#pragma unroll
    for (int j = 0; j < 4; ++j) acc[i][j] = (float4v){0.f, 0.f, 0.f, 0.f};

  for (int k0 = 0; k0 < K; k0 += 64) {
#pragma unroll
    for (int it = 0; it < 4; ++it) {
      int idx = it * 256 + tid;          // 0..1023
      int r = idx >> 3;                  // row 0..127
      int c8 = (idx & 7) << 3;           // k-offset 0..56 step 8
      // A: 8 fp32 (two float4) -> 8 bf16 by >>16 (exact for 0/1).
      uint4 pa = *(const uint4*)(&A[(size_t)(row0 + r) * K + k0 + c8]);
      uint4 pb = *(const uint4*)(&A[(size_t)(row0 + r) * K + k0 + c8 + 4]);
      uint4 st;
      st.x = (pa.x >> 16) | (pa.y & 0xFFFF0000u);
      st.y = (pa.z >> 16) | (pa.w & 0xFFFF0000u);
      st.z = (pb.x >> 16) | (pb.y & 0xFFFF0000u);
      st.w = (pb.z >> 16) | (pb.w & 0xFFFF0000u);
      *(uint4*)(&At[r * 72 + c8]) = st;
      *(uint4*)(&Bt[0][r * 72 + c8]) =
          *(const uint4*)(&Bhi[(size_t)(col0 + r) * K + k0 + c8]);
      *(uint4*)(&Bt[1][r * 72 + c8]) =
          *(const uint4*)(&Blo[(size_t)(col0 + r) * K + k0 + c8]);
    }
    __syncthreads();
#pragma unroll
    for (int ks = 0; ks < 2; ++ks) {
      short8 a[4], bh[4], bl[4];
      const int koff = ks * 32 + quad * 8;
#pragma unroll
      for (int i = 0; i < 4; ++i) {
        a[i] = *(const short8*)(&At[(wm + i * 16 + l15) * 72 + koff]);
        bh[i] = *(const short8*)(&Bt[0][(wn + i * 16 + l15) * 72 + koff]);
        bl[i] = *(const short8*)(&Bt[1][(wn + i * 16 + l15) * 72 + koff]);
      }
#pragma unroll
      for (int i = 0; i < 4; ++i)
#pragma unroll
        for (int j = 0; j < 4; ++j) {
          acc[i][j] = __builtin_amdgcn_mfma_f32_16x16x32_bf16(a[i], bh[j], acc[i][j], 0, 0, 0);
          acc[i][j] = __builtin_amdgcn_mfma_f32_16x16x32_bf16(a[i], bl[j], acc[i][j], 0, 0, 0);
        }
    }
    __syncthreads();
  }
#pragma unroll
  for (int j = 0; j < 4; ++j) {
    const int col = col0 + wn + j * 16 + l15;
    const float bv = bias ? bias[col] : 0.f;
#pragma unroll
    for (int i = 0; i < 4; ++i) {
#pragma unroll
      for (int r = 0; r < 4; ++r) {
        int row = row0 + wm + i * 16 + quad * 4 + r;
        C[(size_t)row * N + col] = acc[i][j][r] + bv;
      }
    }
  }
}

// ---------------------------------------------------------------- LIF scan #1
__global__ __launch_bounds__(256) void k_lif1(float* __restrict__ p) {
  const int id = blockIdx.x * 256 + threadIdx.x;  // 0..32767
  const size_t base = (size_t)(id >> 9) * (T_STEPS * HID) + (id & 511);
  float mem = 0.f;
  for (int t0 = 0; t0 < T_STEPS; t0 += 8) {
    float v[8];
#pragma unroll
    for (int j = 0; j < 8; ++j) v[j] = p[base + (size_t)(t0 + j) * HID];
#pragma unroll
    for (int j = 0; j < 8; ++j) {
      float nm = BETA * mem + v[j];
      float sp = nm > THR ? 1.0f : 0.0f;
      p[base + (size_t)(t0 + j) * HID] = sp;
      mem = nm - sp;
    }
  }
}

// ---------------------------------------------------------------- recurrent scan (== R3)
__global__ __launch_bounds__(512) void k_recurrent_cp(
    const float* __restrict__ W, const float* __restrict__ b_hh,
    float* __restrict__ rp, float* __restrict__ P) {
  const int tid = threadIdx.x;
  const int grp = blockIdx.x >> 3;
  const int j = blockIdx.x & 7;
  const int seg = tid >> 6;
  const int gl = tid & 63;
  const int g0 = j << 6;

  __shared__ float memLDS[2][HID];
  __shared__ float scratch[8][2][64];

  for (int i = tid; i < 2 * HID; i += 512) ((float*)memLDS)[i] = 0.f;

  float Wreg[64];
  {
    const float* wrow = W + (size_t)(g0 + gl) * HID + (seg << 6);
#pragma unroll
    for (int k4 = 0; k4 < 16; ++k4) {
      float4 w4 = *(const float4*)(wrow + 4 * k4);
      Wreg[4 * k4 + 0] = w4.x; Wreg[4 * k4 + 1] = w4.y;
      Wreg[4 * k4 + 2] = w4.z; Wreg[4 * k4 + 3] = w4.w;
    }
  }

  const int ob = tid >> 6;
  const int ogl = tid & 63;
  const int og = g0 + ogl;
  const size_t rp_base = (size_t)(grp * 2 + ob) * (T_STEPS * HID) + og;
  float bhh_v = 0.f;
  if (tid < 128) bhh_v = b_hh[og];

  const int rg = (tid < g0) ? tid : tid + 64;

  const uint32_t* Pu = (const uint32_t*)P;
  float* Pf = P;

  __syncthreads();

  for (int t = 0; t < T_STEPS; ++t) {
    float ip_v = 0.f;
    if (tid < 128) ip_v = rp[rp_base + (size_t)t * HID];

    if (t > 0 && tid < 448) {
      const size_t slot = ((size_t)(t - 1) * 32 + grp) * 1024;
      uint32_t u0 = __hip_atomic_load(Pu + slot + rg, __ATOMIC_RELAXED,
                                      __HIP_MEMORY_SCOPE_AGENT);
      uint32_t u1 = __hip_atomic_load(Pu + slot + 512 + rg, __ATOMIC_RELAXED,
                                      __HIP_MEMORY_SCOPE_AGENT);
      while (u0 == SENT || u1 == SENT) {
        __builtin_amdgcn_s_sleep(1);
        if (u0 == SENT)
          u0 = __hip_atomic_load(Pu + slot + rg, __ATOMIC_RELAXED,
                                 __HIP_MEMORY_SCOPE_AGENT);
        if (u1 == SENT)
          u1 = __hip_atomic_load(Pu + slot + 512 + rg, __ATOMIC_RELAXED,
                                 __HIP_MEMORY_SCOPE_AGENT);
      }
      memLDS[0][rg] = __uint_as_float(u0);
      memLDS[1][rg] = __uint_as_float(u1);
    }
    __syncthreads();

    float p0a = 0.f, p0b = 0.f, p1a = 0.f, p1b = 0.f;
    {
      const float4* m0 = (const float4*)&memLDS[0][seg << 6];
      const float4* m1 = (const float4*)&memLDS[1][seg << 6];
#pragma unroll
      for (int k4 = 0; k4 < 16; ++k4) {
        float4 a = m0[k4];
        float4 b = m1[k4];
        p0a = fmaf(Wreg[4 * k4 + 0], a.x, p0a);
        p0b = fmaf(Wreg[4 * k4 + 1], a.y, p0b);
        p0a = fmaf(Wreg[4 * k4 + 2], a.z, p0a);
        p0b = fmaf(Wreg[4 * k4 + 3], a.w, p0b);
        p1a = fmaf(Wreg[4 * k4 + 0], b.x, p1a);
        p1b = fmaf(Wreg[4 * k4 + 1], b.y, p1b);
        p1a = fmaf(Wreg[4 * k4 + 2], b.z, p1a);
        p1b = fmaf(Wreg[4 * k4 + 3], b.w, p1b);
      }
    }
    scratch[seg][0][gl] = p0a + p0b;
    scratch[seg][1][gl] = p1a + p1b;
    __syncthreads();

    if (tid < 128) {
      float s = 0.f;
#pragma unroll
      for (int ss = 0; ss < 8; ++ss) s += scratch[ss][ob][ogl];
      const float m_old = memLDS[ob][og];
      const float nm = BETA * m_old + ip_v + s + bhh_v;
      const float sp = nm > THR ? 1.0f : 0.0f;
      rp[rp_base + (size_t)t * HID] = sp;
      const float mnew = nm - sp;
      memLDS[ob][og] = mnew;
      const size_t slot = ((size_t)t * 32 + grp) * 1024;
      __hip_atomic_store(Pf + slot + (size_t)ob * 512 + og, mnew,
                         __ATOMIC_RELAXED, __HIP_MEMORY_SCOPE_AGENT);
    }
  }
}

// ---------------------------------------------------------------- attend + threshold
// out[b,o] = (b_out[o] + sum_t attn[t,o]*op[(b,t),o]) > 1
__global__ __launch_bounds__(256) void k_attend(
    const float* __restrict__ op, const float* __restrict__ attn,
    const float* __restrict__ b_out, float* __restrict__ out) {
  const int b = blockIdx.x;
  const int o = threadIdx.x;
  float s = b_out[o];
  const float* opb = op + (size_t)b * T_STEPS * OUT_DIM + o;
  for (int t0 = 0; t0 < T_STEPS; t0 += 8) {
    float av[8], pv[8];
#pragma unroll
    for (int j = 0; j < 8; ++j) {
      av[j] = attn[(size_t)(t0 + j) * OUT_DIM + o];
      pv[j] = opb[(size_t)(t0 + j) * OUT_DIM];
    }
#pragma unroll
    for (int j = 0; j < 8; ++j) s = fmaf(av[j], pv[j], s);
  }
  out[b * OUT_DIM + o] = s > THR ? 1.0f : 0.0f;
}

// ---------------------------------------------------------------- launch
extern "C" void kernel_launch(void* const* d_in, const int* in_sizes, int n_in,
                              void* d_out, int out_size, void* d_ws, size_t ws_size,
                              hipStream_t stream) {
  (void)in_sizes; (void)n_in; (void)out_size; (void)ws_size;
  const float* x     = (const float*)d_in[0];
  const float* W_in  = (const float*)d_in[1];
  const float* b_in  = (const float*)d_in[2];
  const float* W_ih  = (const float*)d_in[3];
  const float* b_ih  = (const float*)d_in[4];
  const float* W_hh  = (const float*)d_in[5];
  const float* b_hh  = (const float*)d_in[6];
  const float* W_out = (const float*)d_in[7];
  const float* b_out = (const float*)d_in[8];
  const float* TA    = (const float*)d_in[9];

  float* ws = (float*)d_ws;
  float* proj  = ws;                           // 16.78M floats: GEMM1 out / P / out_proj
  float* rproj = proj + (size_t)32768 * 512;   // 16.78M floats: x-splits, then GEMM2 out
  float* attn  = rproj + (size_t)32768 * 512;  // 131072 floats
  // bf16 split tables (ushort), after attn:
  ushort_t* wih_hi = (ushort_t*)(attn + 512 * 256);
  ushort_t* wih_lo = wih_hi + 512 * 512;
  ushort_t* win_hi = wih_lo + 512 * 512;
  ushort_t* win_lo = win_hi + 512 * 256;
  ushort_t* wout_hi = win_lo + 512 * 256;
  ushort_t* wout_lo = wout_hi + 256 * 512;
  // x splits alias rproj (dead until GEMM2 writes it):
  ushort_t* x_hi = (ushort_t*)rproj;
  ushort_t* x_lo = x_hi + (size_t)32768 * 256;
  float* P = proj;            // exchange slots [t][grp][b][g]
  float* out_proj = proj;     // (b*T, O) fp32, written after recurrent

  k_softmax_t<<<8, 256, 0, stream>>>(TA, attn);
  k_split<<<4096, 256, 0, stream>>>(x, x_hi, x_lo, 32768 * 256);
  k_split<<<512, 256, 0, stream>>>(W_in, win_hi, win_lo, 512 * 256);
  k_split<<<512, 256, 0, stream>>>(W_ih, wih_hi, wih_lo, 512 * 512);
  k_split<<<512, 256, 0, stream>>>(W_out, wout_hi, wout_lo, 256 * 512);

  // GEMM1: proj = x @ W_in^T + b_in   (M=32768, N=512, K=256)
  k_gemm_split3<<<dim3(256, 4), 256, 0, stream>>>(
      x_hi, x_lo, win_hi, win_lo, b_in, proj, 32768, 512, 256);
  k_lif1<<<128, 256, 0, stream>>>(proj);
  // GEMM2: rproj = spikes @ W_ih^T + b_ih   (M=32768, N=512, K=512)
  k_gemm_spike2<<<dim3(256, 4), 256, 0, stream>>>(
      proj, wih_hi, wih_lo, b_ih, rproj, 32768, 512, 512);
  k_fill_nan<<<256, 256, 0, stream>>>((uint32_t*)P);  // proj dead after GEMM2
  k_recurrent_cp<<<256, 512, 0, stream>>>(W_hh, b_hh, rproj, P);
  // GEMM3: out_proj = tspikes @ W_out^T   (M=32768, N=256, K=512, no bias)
  k_gemm_spike2<<<dim3(256, 2), 256, 0, stream>>>(
      rproj, wout_hi, wout_lo, nullptr, out_proj, 32768, 256, 512);
  k_attend<<<64, 256, 0, stream>>>(out_proj, attn, b_out, (float*)d_out);
}